// Round 3
// baseline (280.785 us; speedup 1.0000x reference)
//
#include <hip/hip_runtime.h>

// AttentionBlock: GN(8 groups) -> 1x1 conv QKV -> attention (B=16,C=512,N=1024) -> 1x1 proj -> +x
// Strategy: bf16 MFMA GEMM pipeline (m97-structure 128x128 tile), d_out doubles as S scratch.
// Workspace plan (66MB peak, buffers aliased by lifetime):
//   [0,512)        mean        [512,1024) rstd
//   [1KB, ~1.5MB)  wq (qkv_w bf16)      [.., 2.1MB) wp (proj_w bf16)
//   h  @2098176  (B,N,C) bf16 16.8MB   -- dead after QKV gemm -> reused as vt (B,C,N)
//   qkv@18875392 (B,N,3C) bf16 50.3MB  -- dead after vtrans   -> first 16.8MB reused as O
//   S = d_out (B,N,N) bf16 = exactly out_size*4 bytes

typedef __bf16 bf16x8 __attribute__((ext_vector_type(8)));
typedef float f32x4 __attribute__((ext_vector_type(4)));
typedef unsigned short u16x8 __attribute__((ext_vector_type(8)));
typedef unsigned short u16x4 __attribute__((ext_vector_type(4)));

#define DEVINL __device__ __forceinline__

DEVINL float b2f(unsigned short u) {
  unsigned int x = ((unsigned int)u) << 16;
  return __builtin_bit_cast(float, x);
}
DEVINL unsigned short f2b(float f) {  // RNE f32->bf16
  unsigned int x = __builtin_bit_cast(unsigned int, f);
  x += 0x7fffu + ((x >> 16) & 1u);
  return (unsigned short)(x >> 16);
}

DEVINL void gload16(const void* g, void* l) {
  __builtin_amdgcn_global_load_lds(
      (const __attribute__((address_space(1))) unsigned int*)(const void*)g,
      (__attribute__((address_space(3))) unsigned int*)l, 16, 0, 0);
}

// ---------------- fp32 -> bf16 convert (weights) ----------------
__global__ __launch_bounds__(256)
void f2bf_k(const float* __restrict__ in, unsigned short* __restrict__ out, int n4) {
  int i = blockIdx.x * 256 + threadIdx.x;
  if (i < n4) {
    float4 v = ((const float4*)in)[i];
    u16x4 o;
    o[0] = f2b(v.x); o[1] = f2b(v.y); o[2] = f2b(v.z); o[3] = f2b(v.w);
    ((u16x4*)out)[i] = o;
  }
}

// ---------------- GroupNorm stats: 128 groups of 64ch x 1024px (contiguous 65536 floats) ----
__global__ __launch_bounds__(256)
void gn_stats(const float* __restrict__ x, float* __restrict__ mean, float* __restrict__ rstd) {
  const int g = blockIdx.x;
  const float4* p = (const float4*)(x + (long long)g * 65536);
  float s = 0.f, q = 0.f;
  for (int i = threadIdx.x; i < 16384; i += 256) {
    float4 v = p[i];
    s += v.x + v.y + v.z + v.w;
    q += v.x * v.x + v.y * v.y + v.z * v.z + v.w * v.w;
  }
#pragma unroll
  for (int off = 32; off; off >>= 1) { s += __shfl_xor(s, off); q += __shfl_xor(q, off); }
  __shared__ float ss[4], qs[4];
  const int wave = threadIdx.x >> 6, lane = threadIdx.x & 63;
  if (lane == 0) { ss[wave] = s; qs[wave] = q; }
  __syncthreads();
  if (threadIdx.x == 0) {
    float S = ss[0] + ss[1] + ss[2] + ss[3];
    float Q = qs[0] + qs[1] + qs[2] + qs[3];
    float mu = S * (1.f / 65536.f);
    float var = Q * (1.f / 65536.f) - mu * mu;
    mean[g] = mu;
    rstd[g] = rsqrtf(var + 1e-5f);
  }
}

// ---------------- GN apply + transpose: x (b,c,p) fp32 -> h (b,p,c) bf16 ----------------
__global__ __launch_bounds__(256)
void gn_apply_t(const float* __restrict__ x, const float* __restrict__ mean,
                const float* __restrict__ rstd, const float* __restrict__ gw,
                const float* __restrict__ gb, unsigned short* __restrict__ h) {
  const int b = blockIdx.z, ct = blockIdx.y, pt = blockIdx.x;
  const int c0 = ct << 6, p0 = pt << 6;
  const float mu = mean[b * 8 + ct];
  const float rs = rstd[b * 8 + ct];
  __shared__ float t[64][65];
  const int r4 = threadIdx.x >> 6, cl = threadIdx.x & 63;
#pragma unroll
  for (int i = 0; i < 16; ++i) {
    int r = i * 4 + r4;            // channel within tile (group == ct since 64 ch/group)
    int c = c0 + r;
    float v = x[(long long)(b * 512 + c) * 1024 + p0 + cl];
    t[r][cl] = (v - mu) * rs * gw[c] + gb[c];
  }
  __syncthreads();
#pragma unroll
  for (int i = 0; i < 16; ++i) {
    int pr = i * 4 + r4;           // pixel within tile
    h[(long long)(b * 1024 + p0 + pr) * 512 + c0 + cl] = f2b(t[cl][pr]);
  }
}

// ---------------- V transpose: qkv v-slice (b, p, c) -> vt (b, c, p) bf16 ----------------
__global__ __launch_bounds__(256)
void vtrans(const unsigned short* __restrict__ qkv, unsigned short* __restrict__ vt) {
  const int b = blockIdx.z, ct = blockIdx.y, pt = blockIdx.x;
  const int c0 = ct << 6, p0 = pt << 6;
  const unsigned short* src = qkv + (long long)b * 1024 * 1536 + 1024;  // v cols [1024,1536)
  unsigned short* dst = vt + (long long)b * 512 * 1024;
  __shared__ unsigned short t[64][65];
  const int r4 = threadIdx.x >> 6, cl = threadIdx.x & 63;
#pragma unroll
  for (int i = 0; i < 16; ++i) {
    int pr = i * 4 + r4;
    t[pr][cl] = src[(long long)(p0 + pr) * 1536 + c0 + cl];
  }
  __syncthreads();
#pragma unroll
  for (int i = 0; i < 16; ++i) {
    int cr = i * 4 + r4;
    dst[(long long)(c0 + cr) * 1024 + p0 + cl] = t[cl][cr];
  }
}

// ---------------- softmax in-place on S rows (bf16, 1024 per row), one wave per row ------
__global__ __launch_bounds__(256)
void softmax_rows(unsigned short* __restrict__ S) {
  const long long row = (long long)blockIdx.x * 4 + (threadIdx.x >> 6);
  const int lane = threadIdx.x & 63;
  u16x8* p = (u16x8*)(S + row * 1024);
  u16x8 a = p[lane], b = p[64 + lane];
  float v[16];
#pragma unroll
  for (int i = 0; i < 8; ++i) { v[i] = b2f(a[i]); v[8 + i] = b2f(b[i]); }
  float m = v[0];
#pragma unroll
  for (int i = 1; i < 16; ++i) m = fmaxf(m, v[i]);
#pragma unroll
  for (int off = 32; off; off >>= 1) m = fmaxf(m, __shfl_xor(m, off));
  float s = 0.f;
#pragma unroll
  for (int i = 0; i < 16; ++i) { v[i] = __expf(v[i] - m); s += v[i]; }
#pragma unroll
  for (int off = 32; off; off >>= 1) s += __shfl_xor(s, off);
  float inv = 1.f / s;
#pragma unroll
  for (int i = 0; i < 8; ++i) { a[i] = f2b(v[i] * inv); b[i] = f2b(v[8 + i] * inv); }
  p[lane] = a;
  p[64 + lane] = b;
}

// ---------------- batched GEMM, B^T form: C[z][m][n] = sum_k A[z][m][k] * B[z][n][k] ------
// 128x128 tile, BK=64, 4 waves, each wave 64x64 via 4x4 frags of mfma_f32_16x16x32_bf16.
// All dims must be multiples of 128 (rows/cols) and 64 (K) -- true for every call here.
#define RSQRT_C 0.044194173824159216f
enum { EPI_BF16 = 0, EPI_QKV = 1, EPI_PROJ = 2 };

template <int EPI>
__global__ __launch_bounds__(256)
void gemm_bt(const unsigned short* __restrict__ A, int lda, long long sA,
             const unsigned short* __restrict__ B, int ldb, long long sB,
             void* __restrict__ Cv, int ldc, long long sC, int K,
             const float* __restrict__ bias, const float* __restrict__ resid) {
  __shared__ char lds[32768];  // A tile [128][64] bf16 @0, B tile @16384
  const int tid = threadIdx.x;
  const int wave = tid >> 6, lane = tid & 63;
  const int wr = wave >> 1, wc = wave & 1;
  const long long bm = blockIdx.y, bn = blockIdx.x, bz = blockIdx.z;

  const unsigned short* Ab = A + bz * sA + bm * 128 * (long long)lda;
  const unsigned short* Bb = B + bz * sB + bn * 128 * (long long)ldb;

  f32x4 acc[4][4] = {};

  const int frow = lane & 15;
  const int fk = (lane >> 4) << 3;  // 0,8,16,24

  for (int k0 = 0; k0 < K; k0 += 64) {
    // stage A & B tiles: 1024 chunks of 16B each; wave-uniform LDS base + lane*16
#pragma unroll
    for (int i = 0; i < 4; ++i) {
      int chunk = (i << 8) + tid;  // 0..1023
      int r = chunk >> 3, c8 = chunk & 7;
      const unsigned short* ga = Ab + (long long)r * lda + k0 + (c8 << 3);
      const unsigned short* gb = Bb + (long long)r * ldb + k0 + (c8 << 3);
      char* la = lds + (((i << 8) + (wave << 6)) << 4);
      gload16(ga, la);
      gload16(gb, la + 16384);
    }
    __syncthreads();  // drains vmcnt: LDS tiles ready
#pragma unroll
    for (int ks = 0; ks < 2; ++ks) {
      bf16x8 af[4], bfr[4];
#pragma unroll
      for (int f = 0; f < 4; ++f) {
        int ar = (wr << 6) + (f << 4) + frow;
        af[f] = *reinterpret_cast<const bf16x8*>(lds + ((ar << 6) + (ks << 5) + fk) * 2);
        int br = (wc << 6) + (f << 4) + frow;
        bfr[f] = *reinterpret_cast<const bf16x8*>(lds + 16384 + ((br << 6) + (ks << 5) + fk) * 2);
      }
#pragma unroll
      for (int i = 0; i < 4; ++i)
#pragma unroll
        for (int j = 0; j < 4; ++j)
          acc[i][j] = __builtin_amdgcn_mfma_f32_16x16x32_bf16(af[i], bfr[j], acc[i][j], 0, 0, 0);
    }
    __syncthreads();  // all reads done before next stage overwrites LDS
  }

  // epilogue: C row = (lane>>4)*4 + reg, col = lane&15  (verified m89/m91 mapping)
  const int rb = (int)bm * 128 + (wr << 6) + ((lane >> 4) << 2);
  const int cb = (int)bn * 128 + (wc << 6) + (lane & 15);
#pragma unroll
  for (int i = 0; i < 4; ++i) {
#pragma unroll
    for (int j = 0; j < 4; ++j) {
      const int col = cb + (j << 4);
#pragma unroll
      for (int r = 0; r < 4; ++r) {
        const int row = rb + (i << 4) + r;
        float v = acc[i][j][r];
        if constexpr (EPI == EPI_BF16) {
          ((unsigned short*)Cv)[bz * sC + (long long)row * ldc + col] = f2b(v);
        } else if constexpr (EPI == EPI_QKV) {
          v += bias[col];
          if (col < 512) v *= RSQRT_C;  // fold attn scale into q
          ((unsigned short*)Cv)[bz * sC + (long long)row * ldc + col] = f2b(v);
        } else {  // EPI_PROJ: fp32 out + per-row bias + residual
          long long idx = bz * sC + (long long)row * ldc + col;
          ((float*)Cv)[idx] = v + bias[row] + resid[idx];
        }
      }
    }
  }
}

// ---------------- launch ----------------
extern "C" void kernel_launch(void* const* d_in, const int* in_sizes, int n_in,
                              void* d_out, int out_size, void* d_ws, size_t ws_size,
                              hipStream_t stream) {
  const float* x      = (const float*)d_in[0];
  const float* gn_w   = (const float*)d_in[1];
  const float* gn_b   = (const float*)d_in[2];
  const float* qkv_w  = (const float*)d_in[3];
  const float* qkv_b  = (const float*)d_in[4];
  const float* proj_w = (const float*)d_in[5];
  const float* proj_b = (const float*)d_in[6];

  char* ws = (char*)d_ws;
  float* mean          = (float*)(ws + 0);                  // 128 f
  float* rstd          = (float*)(ws + 512);                // 128 f
  unsigned short* wq   = (unsigned short*)(ws + 1024);      // 1536x512 bf16 = 1572864 B
  unsigned short* wp   = (unsigned short*)(ws + 1573888);   // 512x512 bf16  = 524288 B
  unsigned short* h    = (unsigned short*)(ws + 2098176);   // (B,N,C) bf16 16.8MB
  unsigned short* qkv  = (unsigned short*)(ws + 18875392);  // (B,N,3C) bf16 50.3MB [end ~66MB]
  unsigned short* vt   = h;                                 // reuse: h dead after QKV gemm
  unsigned short* O    = qkv;                               // reuse: qkv dead after vtrans
  unsigned short* S    = (unsigned short*)d_out;            // (B,N,N) bf16 = exactly out bytes

  // weights -> bf16
  f2bf_k<<<768, 256, 0, stream>>>(qkv_w, wq, 196608);
  f2bf_k<<<256, 256, 0, stream>>>(proj_w, wp, 65536);
  // GroupNorm
  gn_stats<<<128, 256, 0, stream>>>(x, mean, rstd);
  gn_apply_t<<<dim3(16, 8, 16), 256, 0, stream>>>(x, mean, rstd, gn_w, gn_b, h);
  // QKV: (16384x512) x (1536x512)^T -> (16384x1536), bias + q-scale
  gemm_bt<EPI_QKV><<<dim3(12, 128, 1), 256, 0, stream>>>(
      h, 512, 0, wq, 512, 0, qkv, 1536, 0, 512, qkv_b, nullptr);
  // S = q k^T per batch: (1024x512)x(1024x512)^T -> (1024x1024) bf16 in d_out
  gemm_bt<EPI_BF16><<<dim3(8, 8, 16), 256, 0, stream>>>(
      qkv, 1536, 1024LL * 1536, qkv + 512, 1536, 1024LL * 1536,
      S, 1024, 1024LL * 1024, 512, nullptr, nullptr);
  // softmax rows in place
  softmax_rows<<<4096, 256, 0, stream>>>(S);
  // V^T: extract v from qkv into vt (b,c,p); after this, qkv buffer is dead
  vtrans<<<dim3(16, 8, 16), 256, 0, stream>>>(qkv, vt);
  // O = P V : (1024x1024)x(512x1024)^T -> (1024x512) bf16  (O aliases dead qkv)
  gemm_bt<EPI_BF16><<<dim3(4, 8, 16), 256, 0, stream>>>(
      S, 1024, 1024LL * 1024, vt, 1024, 512LL * 1024,
      O, 512, 1024LL * 512, 1024, nullptr, nullptr);
  // out^T form proj: (512x512)x(1024x512)^T -> (512x1024) fp32 + bias + residual
  gemm_bt<EPI_PROJ><<<dim3(8, 4, 16), 256, 0, stream>>>(
      wp, 512, 0, O, 512, 1024LL * 512,
      d_out, 1024, 512LL * 1024, 512, proj_b, x);
}

// Round 4
// 243.768 us; speedup vs baseline: 1.1519x; 1.1519x over previous
//
#include <hip/hip_runtime.h>

// AttentionBlock: GN(8 groups) -> 1x1 conv QKV -> attention (B=16,C=512,N=1024) -> 1x1 proj -> +x
// R4: GEMM K-loop rewritten: 2-deep LDS double-buffer + counted vmcnt(8) (T3/T4 minimum),
//     LDS XOR-swizzle both-sides (T2), setprio around MFMA (T5), XCD-chunked grid (T1).
//     Same verified 128x128 tile / fragment / C-layout math as the passing R3 kernel.
// Workspace plan (66MB peak): see R3 comments; S lives in d_out.

typedef __bf16 bf16x8 __attribute__((ext_vector_type(8)));
typedef float f32x4 __attribute__((ext_vector_type(4)));
typedef unsigned short u16x8 __attribute__((ext_vector_type(8)));
typedef unsigned short u16x4 __attribute__((ext_vector_type(4)));

#define DEVINL __device__ __forceinline__

DEVINL float b2f(unsigned short u) {
  unsigned int x = ((unsigned int)u) << 16;
  return __builtin_bit_cast(float, x);
}
DEVINL unsigned short f2b(float f) {  // RNE f32->bf16
  unsigned int x = __builtin_bit_cast(unsigned int, f);
  x += 0x7fffu + ((x >> 16) & 1u);
  return (unsigned short)(x >> 16);
}

DEVINL void gload16(const void* g, void* l) {
  __builtin_amdgcn_global_load_lds(
      (const __attribute__((address_space(1))) unsigned int*)(const void*)g,
      (__attribute__((address_space(3))) unsigned int*)l, 16, 0, 0);
}

// ---------------- fp32 -> bf16 convert (weights) ----------------
__global__ __launch_bounds__(256)
void f2bf_k(const float* __restrict__ in, unsigned short* __restrict__ out, int n4) {
  int i = blockIdx.x * 256 + threadIdx.x;
  if (i < n4) {
    float4 v = ((const float4*)in)[i];
    u16x4 o;
    o[0] = f2b(v.x); o[1] = f2b(v.y); o[2] = f2b(v.z); o[3] = f2b(v.w);
    ((u16x4*)out)[i] = o;
  }
}

// ---------------- GroupNorm stats: 128 groups of 64ch x 1024px ----------------
__global__ __launch_bounds__(256)
void gn_stats(const float* __restrict__ x, float* __restrict__ mean, float* __restrict__ rstd) {
  const int g = blockIdx.x;
  const float4* p = (const float4*)(x + (long long)g * 65536);
  float s = 0.f, q = 0.f;
  for (int i = threadIdx.x; i < 16384; i += 256) {
    float4 v = p[i];
    s += v.x + v.y + v.z + v.w;
    q += v.x * v.x + v.y * v.y + v.z * v.z + v.w * v.w;
  }
#pragma unroll
  for (int off = 32; off; off >>= 1) { s += __shfl_xor(s, off); q += __shfl_xor(q, off); }
  __shared__ float ss[4], qs[4];
  const int wave = threadIdx.x >> 6, lane = threadIdx.x & 63;
  if (lane == 0) { ss[wave] = s; qs[wave] = q; }
  __syncthreads();
  if (threadIdx.x == 0) {
    float S = ss[0] + ss[1] + ss[2] + ss[3];
    float Q = qs[0] + qs[1] + qs[2] + qs[3];
    float mu = S * (1.f / 65536.f);
    float var = Q * (1.f / 65536.f) - mu * mu;
    mean[g] = mu;
    rstd[g] = rsqrtf(var + 1e-5f);
  }
}

// ---------------- GN apply + transpose: x (b,c,p) fp32 -> h (b,p,c) bf16 ----------------
__global__ __launch_bounds__(256)
void gn_apply_t(const float* __restrict__ x, const float* __restrict__ mean,
                const float* __restrict__ rstd, const float* __restrict__ gw,
                const float* __restrict__ gb, unsigned short* __restrict__ h) {
  const int b = blockIdx.z, ct = blockIdx.y, pt = blockIdx.x;
  const int c0 = ct << 6, p0 = pt << 6;
  const float mu = mean[b * 8 + ct];
  const float rs = rstd[b * 8 + ct];
  __shared__ float t[64][65];
  const int r4 = threadIdx.x >> 6, cl = threadIdx.x & 63;
#pragma unroll
  for (int i = 0; i < 16; ++i) {
    int r = i * 4 + r4;
    int c = c0 + r;
    float v = x[(long long)(b * 512 + c) * 1024 + p0 + cl];
    t[r][cl] = (v - mu) * rs * gw[c] + gb[c];
  }
  __syncthreads();
#pragma unroll
  for (int i = 0; i < 16; ++i) {
    int pr = i * 4 + r4;
    h[(long long)(b * 1024 + p0 + pr) * 512 + c0 + cl] = f2b(t[cl][pr]);
  }
}

// ---------------- V transpose: qkv v-slice (b, p, c) -> vt (b, c, p) bf16 ----------------
__global__ __launch_bounds__(256)
void vtrans(const unsigned short* __restrict__ qkv, unsigned short* __restrict__ vt) {
  const int b = blockIdx.z, ct = blockIdx.y, pt = blockIdx.x;
  const int c0 = ct << 6, p0 = pt << 6;
  const unsigned short* src = qkv + (long long)b * 1024 * 1536 + 1024;
  unsigned short* dst = vt + (long long)b * 512 * 1024;
  __shared__ unsigned short t[64][65];
  const int r4 = threadIdx.x >> 6, cl = threadIdx.x & 63;
#pragma unroll
  for (int i = 0; i < 16; ++i) {
    int pr = i * 4 + r4;
    t[pr][cl] = src[(long long)(p0 + pr) * 1536 + c0 + cl];
  }
  __syncthreads();
#pragma unroll
  for (int i = 0; i < 16; ++i) {
    int cr = i * 4 + r4;
    dst[(long long)(c0 + cr) * 1024 + p0 + cl] = t[cl][cr];
  }
}

// ---------------- softmax in-place on S rows (bf16, 1024 per row) ----------------
__global__ __launch_bounds__(256)
void softmax_rows(unsigned short* __restrict__ S) {
  const long long row = (long long)blockIdx.x * 4 + (threadIdx.x >> 6);
  const int lane = threadIdx.x & 63;
  u16x8* p = (u16x8*)(S + row * 1024);
  u16x8 a = p[lane], b = p[64 + lane];
  float v[16];
#pragma unroll
  for (int i = 0; i < 8; ++i) { v[i] = b2f(a[i]); v[8 + i] = b2f(b[i]); }
  float m = v[0];
#pragma unroll
  for (int i = 1; i < 16; ++i) m = fmaxf(m, v[i]);
#pragma unroll
  for (int off = 32; off; off >>= 1) m = fmaxf(m, __shfl_xor(m, off));
  float s = 0.f;
#pragma unroll
  for (int i = 0; i < 16; ++i) { v[i] = __expf(v[i] - m); s += v[i]; }
#pragma unroll
  for (int off = 32; off; off >>= 1) s += __shfl_xor(s, off);
  float inv = 1.f / s;
#pragma unroll
  for (int i = 0; i < 8; ++i) { a[i] = f2b(v[i] * inv); b[i] = f2b(v[8 + i] * inv); }
  p[lane] = a;
  p[64 + lane] = b;
}

// ---------------- batched GEMM, B^T form: C[z][m][n] = sum_k A[z][m][k]*B[z][n][k] ------
// 128x128 tile, BK=64, 4 waves. R4 pipeline:
//   2-deep LDS dbuf (2 x 32KB). Per iter: [bar1] compute buf[cur] [bar2] stage kt+2 into
//   buf[cur], vmcnt(8) (== tile kt+1's 8 loads landed; kt+2's 8 may fly). Raw s_barrier
//   (no compiler vmcnt(0) drain). T2 swizzle: LDS[d ^ ((row&7)<<4)] = G[d]; write side via
//   pre-swizzled per-lane global src (gload_lds dest stays linear), read side XOR on addr.
//   Round-trip verified: row5,kb32 -> LDS 752 -> chunk47 -> src kb (7^5)<<4 = 32. OK.
#define RSQRT_C 0.044194173824159216f
enum { EPI_BF16 = 0, EPI_QKV = 1, EPI_PROJ = 2 };

DEVINL void stage_tile(const unsigned short* __restrict__ Ab,
                       const unsigned short* __restrict__ Bb,
                       int lda, int ldb, int k0, char* lb, int tid, int wave) {
#pragma unroll
  for (int i = 0; i < 4; ++i) {
    const int c = (i << 8) + tid;            // chunk 0..1023 (16B each)
    const int r = c >> 3;                    // tile row 0..127
    const int sk = ((c & 7) ^ (r & 7)) << 3; // pre-swizzled k-offset (shorts)
    char* la = lb + (((i << 8) + (wave << 6)) << 4);  // wave-uniform dest + lane*16
    gload16(Ab + (long long)r * lda + k0 + sk, la);
    gload16(Bb + (long long)r * ldb + k0 + sk, la + 16384);
  }
}

template <int EPI>
__global__ __launch_bounds__(256, 2)
void gemm_bt(const unsigned short* __restrict__ A, int lda, long long sA,
             const unsigned short* __restrict__ B, int ldb, long long sB,
             void* __restrict__ Cv, int ldc, long long sC, int K,
             const float* __restrict__ bias, const float* __restrict__ resid,
             int gx, int gy) {
  __shared__ char lds[65536];  // buf t: A tile @ t*32768, B tile @ t*32768+16384
  const int tid = threadIdx.x;
  const int wave = tid >> 6, lane = tid & 63;
  const int wr = wave >> 1, wc = wave & 1;

  // T1: bijective XCD-chunked remap (all launches have nwg % 8 == 0)
  const int nwg = gridDim.x;
  const int id0 = blockIdx.x;
  const int id = (id0 & 7) * (nwg >> 3) + (id0 >> 3);
  const int bn = id % gx;
  const int t1 = id / gx;
  const int bm = t1 % gy;
  const int bz = t1 / gy;

  const unsigned short* Ab = A + (long long)bz * sA + (long long)bm * 128 * lda;
  const unsigned short* Bb = B + (long long)bz * sB + (long long)bn * 128 * ldb;

  f32x4 acc[4][4] = {};
  const int frow = lane & 15;
  const int fkb = (lane >> 4) << 4;      // byte offset of lane's 16B within the 64B k-half
  const int swr = (frow & 7) << 4;       // read-side swizzle term (row&7 == frow&7)
  const int NT = K >> 6;                 // >= 8 for all calls

  stage_tile(Ab, Bb, lda, ldb, 0, lds, tid, wave);
  stage_tile(Ab, Bb, lda, ldb, 64, lds + 32768, tid, wave);
  asm volatile("s_waitcnt vmcnt(8)" ::: "memory");  // tile 0 landed (tile 1 in flight)

  for (int kt = 0; kt < NT; ++kt) {
    const int cur = kt & 1;
    __builtin_amdgcn_s_barrier();        // bar1: tile kt staged by ALL waves
    asm volatile("" ::: "memory");
    const char* lb = lds + cur * 32768;
    __builtin_amdgcn_s_setprio(1);
#pragma unroll
    for (int ks = 0; ks < 2; ++ks) {
      bf16x8 af[4], bfr[4];
      const int kb = (ks << 6) + fkb;
#pragma unroll
      for (int f = 0; f < 4; ++f) {
        const int ar = (wr << 6) + (f << 4) + frow;
        af[f] = *reinterpret_cast<const bf16x8*>(lb + ar * 128 + (kb ^ swr));
        const int br = (wc << 6) + (f << 4) + frow;
        bfr[f] = *reinterpret_cast<const bf16x8*>(lb + 16384 + br * 128 + (kb ^ swr));
      }
#pragma unroll
      for (int i = 0; i < 4; ++i)
#pragma unroll
        for (int j = 0; j < 4; ++j)
          acc[i][j] = __builtin_amdgcn_mfma_f32_16x16x32_bf16(af[i], bfr[j], acc[i][j], 0, 0, 0);
    }
    __builtin_amdgcn_s_setprio(0);
    asm volatile("" ::: "memory");
    __builtin_amdgcn_s_barrier();        // bar2: all waves done reading buf[cur]
    if (kt + 2 < NT) {
      stage_tile(Ab, Bb, lda, ldb, (kt + 2) << 6, lds + cur * 32768, tid, wave);
      asm volatile("s_waitcnt vmcnt(8)" ::: "memory");  // tile kt+1 landed
    } else if (kt + 2 == NT) {
      asm volatile("s_waitcnt vmcnt(0)" ::: "memory");  // last tile landed
    }
  }

  // epilogue: C row = (lane>>4)*4 + reg, col = lane&15 (verified m89/m91; R3 passed)
  const int rb = bm * 128 + (wr << 6) + ((lane >> 4) << 2);
  const int cb = bn * 128 + (wc << 6) + (lane & 15);
#pragma unroll
  for (int i = 0; i < 4; ++i) {
#pragma unroll
    for (int j = 0; j < 4; ++j) {
      const int col = cb + (j << 4);
#pragma unroll
      for (int r = 0; r < 4; ++r) {
        const int row = rb + (i << 4) + r;
        float v = acc[i][j][r];
        if constexpr (EPI == EPI_BF16) {
          ((unsigned short*)Cv)[(long long)bz * sC + (long long)row * ldc + col] = f2b(v);
        } else if constexpr (EPI == EPI_QKV) {
          v += bias[col];
          if (col < 512) v *= RSQRT_C;  // fold attn scale into q
          ((unsigned short*)Cv)[(long long)bz * sC + (long long)row * ldc + col] = f2b(v);
        } else {  // EPI_PROJ: fp32 out + per-row bias + residual
          long long idx = (long long)bz * sC + (long long)row * ldc + col;
          ((float*)Cv)[idx] = v + bias[row] + resid[idx];
        }
      }
    }
  }
}

// ---------------- launch ----------------
extern "C" void kernel_launch(void* const* d_in, const int* in_sizes, int n_in,
                              void* d_out, int out_size, void* d_ws, size_t ws_size,
                              hipStream_t stream) {
  const float* x      = (const float*)d_in[0];
  const float* gn_w   = (const float*)d_in[1];
  const float* gn_b   = (const float*)d_in[2];
  const float* qkv_w  = (const float*)d_in[3];
  const float* qkv_b  = (const float*)d_in[4];
  const float* proj_w = (const float*)d_in[5];
  const float* proj_b = (const float*)d_in[6];

  char* ws = (char*)d_ws;
  float* mean          = (float*)(ws + 0);                  // 128 f
  float* rstd          = (float*)(ws + 512);                // 128 f
  unsigned short* wq   = (unsigned short*)(ws + 1024);      // 1536x512 bf16
  unsigned short* wp   = (unsigned short*)(ws + 1573888);   // 512x512 bf16
  unsigned short* h    = (unsigned short*)(ws + 2098176);   // (B,N,C) bf16 16.8MB
  unsigned short* qkv  = (unsigned short*)(ws + 18875392);  // (B,N,3C) bf16 50.3MB
  unsigned short* vt   = h;                                 // h dead after QKV gemm
  unsigned short* O    = qkv;                               // qkv dead after vtrans
  unsigned short* S    = (unsigned short*)d_out;            // (B,N,N) bf16

  f2bf_k<<<768, 256, 0, stream>>>(qkv_w, wq, 196608);
  f2bf_k<<<256, 256, 0, stream>>>(proj_w, wp, 65536);
  gn_stats<<<128, 256, 0, stream>>>(x, mean, rstd);
  gn_apply_t<<<dim3(16, 8, 16), 256, 0, stream>>>(x, mean, rstd, gn_w, gn_b, h);
  // QKV: (16384x512) x (1536x512)^T -> (16384x1536); grid 12x128 flattened
  gemm_bt<EPI_QKV><<<1536, 256, 0, stream>>>(
      h, 512, 0, wq, 512, 0, qkv, 1536, 0, 512, qkv_b, nullptr, 12, 128);
  // S = q k^T per batch: grid 8x8x16 flattened
  gemm_bt<EPI_BF16><<<1024, 256, 0, stream>>>(
      qkv, 1536, 1024LL * 1536, qkv + 512, 1536, 1024LL * 1536,
      S, 1024, 1024LL * 1024, 512, nullptr, nullptr, 8, 8);
  softmax_rows<<<4096, 256, 0, stream>>>(S);
  vtrans<<<dim3(16, 8, 16), 256, 0, stream>>>(qkv, vt);
  // O = P V: grid 4x8x16 flattened
  gemm_bt<EPI_BF16><<<512, 256, 0, stream>>>(
      S, 1024, 1024LL * 1024, vt, 1024, 512LL * 1024,
      O, 512, 1024LL * 512, 1024, nullptr, nullptr, 4, 8);
  // proj (out^T form): grid 8x4x16 flattened
  gemm_bt<EPI_PROJ><<<512, 256, 0, stream>>>(
      wp, 512, 0, O, 512, 1024LL * 512,
      d_out, 1024, 512LL * 1024, 512, proj_b, x, 8, 4);
}

// Round 7
// 237.530 us; speedup vs baseline: 1.1821x; 1.0263x over previous
//
#include <hip/hip_runtime.h>

// AttentionBlock: GN(8 groups) -> 1x1 conv QKV -> attention (B=16,C=512,N=1024) -> 1x1 proj -> +x
// R5: dispatch-count reduction (10 -> 7): f2bf merged; gn_stats+gn_apply fused (one block per
//     group, stats then L2-hot apply+transpose); vtrans eliminated (QKV epilogue writes V
//     transposed directly). GEMM core identical to R4 (2-deep dbuf, vmcnt(8), T2 swizzle,
//     setprio, XCD-chunked grid).
// Workspace: wq/wp @1KB..2.1MB; h @2098176 (16.8MB, dead after QKV -> reused as O);
//            qkv(q,k only, ld1024) @18875392 (33.6MB); vt @52429824 (16.8MB); peak 69.2MB.
//            S = d_out (B,N,N) bf16.

typedef __bf16 bf16x8 __attribute__((ext_vector_type(8)));
typedef float f32x4 __attribute__((ext_vector_type(4)));
typedef unsigned short u16x8 __attribute__((ext_vector_type(8)));
typedef unsigned short u16x4 __attribute__((ext_vector_type(4)));

#define DEVINL __device__ __forceinline__

DEVINL float b2f(unsigned short u) {
  unsigned int x = ((unsigned int)u) << 16;
  return __builtin_bit_cast(float, x);
}
DEVINL unsigned short f2b(float f) {  // RNE f32->bf16
  unsigned int x = __builtin_bit_cast(unsigned int, f);
  x += 0x7fffu + ((x >> 16) & 1u);
  return (unsigned short)(x >> 16);
}

DEVINL void gload16(const void* g, void* l) {
  __builtin_amdgcn_global_load_lds(
      (const __attribute__((address_space(1))) unsigned int*)(const void*)g,
      (__attribute__((address_space(3))) unsigned int*)l, 16, 0, 0);
}

// ---------------- fp32 -> bf16 convert, both weight mats in one dispatch ----------------
__global__ __launch_bounds__(256)
void f2bf_all(const float* __restrict__ qw, const float* __restrict__ pw,
              unsigned short* __restrict__ wq, unsigned short* __restrict__ wp) {
  const int i = blockIdx.x * 256 + threadIdx.x;  // 0..262143 (196608 qkv + 65536 proj)
  const bool isq = i < 196608;
  const int j = isq ? i : i - 196608;
  float4 v = isq ? ((const float4*)qw)[j] : ((const float4*)pw)[j];
  u16x4 o;
  o[0] = f2b(v.x); o[1] = f2b(v.y); o[2] = f2b(v.z); o[3] = f2b(v.w);
  if (isq) ((u16x4*)wq)[j] = o; else ((u16x4*)wp)[j] = o;
}

// ---------------- fused GroupNorm: stats + apply + transpose, one block per (b,g) --------
// Group (b,g) = 64 ch x 1024 px contiguous 65536 floats. Phase1: mean/rstd. Phase2: 16
// pixel-tiles of 64x64, normalize + LDS transpose, write h (b,p,c) bf16. Second pass reads
// are L2-hot (256KB/group).
__global__ __launch_bounds__(512)
void gn_fused(const float* __restrict__ x, const float* __restrict__ gw,
              const float* __restrict__ gb, unsigned short* __restrict__ h) {
  const int b = blockIdx.x >> 3, g = blockIdx.x & 7;
  const float* base = x + (long long)(b * 512 + g * 64) * 1024;
  float s = 0.f, q = 0.f;
  for (int i = threadIdx.x; i < 16384; i += 512) {
    float4 v = ((const float4*)base)[i];
    s += v.x + v.y + v.z + v.w;
    q += v.x * v.x + v.y * v.y + v.z * v.z + v.w * v.w;
  }
#pragma unroll
  for (int off = 32; off; off >>= 1) { s += __shfl_xor(s, off); q += __shfl_xor(q, off); }
  __shared__ float ss[8], qs[8], stats[2];
  const int wave = threadIdx.x >> 6, lane = threadIdx.x & 63;
  if (lane == 0) { ss[wave] = s; qs[wave] = q; }
  __syncthreads();
  if (threadIdx.x == 0) {
    float S = 0.f, Q = 0.f;
#pragma unroll
    for (int w = 0; w < 8; ++w) { S += ss[w]; Q += qs[w]; }
    float mu = S * (1.f / 65536.f);
    float var = Q * (1.f / 65536.f) - mu * mu;
    stats[0] = mu;
    stats[1] = rsqrtf(var + 1e-5f);
  }
  __syncthreads();
  const float mu = stats[0], rs = stats[1];
  __shared__ float t[64][65];
  const int r8 = threadIdx.x >> 6, cl = threadIdx.x & 63;  // 8 row-groups x 64 cols
  for (int pt = 0; pt < 16; ++pt) {
    const int p0 = pt << 6;
#pragma unroll
    for (int i = 0; i < 8; ++i) {
      int c = i * 8 + r8;  // channel within group
      float v = base[(long long)c * 1024 + p0 + cl];
      t[c][cl] = (v - mu) * rs * gw[g * 64 + c] + gb[g * 64 + c];
    }
    __syncthreads();
#pragma unroll
    for (int i = 0; i < 8; ++i) {
      int pr = i * 8 + r8;  // pixel within tile
      h[(long long)(b * 1024 + p0 + pr) * 512 + g * 64 + cl] = f2b(t[cl][pr]);
    }
    __syncthreads();
  }
}

// ---------------- softmax in-place on S rows (bf16, 1024 per row) ----------------
__global__ __launch_bounds__(256)
void softmax_rows(unsigned short* __restrict__ S) {
  const long long row = (long long)blockIdx.x * 4 + (threadIdx.x >> 6);
  const int lane = threadIdx.x & 63;
  u16x8* p = (u16x8*)(S + row * 1024);
  u16x8 a = p[lane], b = p[64 + lane];
  float v[16];
#pragma unroll
  for (int i = 0; i < 8; ++i) { v[i] = b2f(a[i]); v[8 + i] = b2f(b[i]); }
  float m = v[0];
#pragma unroll
  for (int i = 1; i < 16; ++i) m = fmaxf(m, v[i]);
#pragma unroll
  for (int off = 32; off; off >>= 1) m = fmaxf(m, __shfl_xor(m, off));
  float s = 0.f;
#pragma unroll
  for (int i = 0; i < 16; ++i) { v[i] = __expf(v[i] - m); s += v[i]; }
#pragma unroll
  for (int off = 32; off; off >>= 1) s += __shfl_xor(s, off);
  float inv = 1.f / s;
#pragma unroll
  for (int i = 0; i < 8; ++i) { a[i] = f2b(v[i] * inv); b[i] = f2b(v[8 + i] * inv); }
  p[lane] = a;
  p[64 + lane] = b;
}

// ---------------- batched GEMM, B^T form: C[z][m][n] = sum_k A[z][m][k]*B[z][n][k] ------
// 128x128 tile, BK=64, 4 waves, 2-deep LDS dbuf + counted vmcnt(8), T2 swizzle both-sides,
// setprio around MFMA, XCD-chunked flattened grid. Verified R3/R4.
// EPI_QKV: C=qkv ld1024 for col<1024 (bias, q-scale); col>=1024 -> vt[b][c'][p] transposed
//          (packed u16x4 along p; tile rows never cross a batch since 128 | 1024).
#define RSQRT_C 0.044194173824159216f
enum { EPI_BF16 = 0, EPI_QKV = 1, EPI_PROJ = 2 };

DEVINL void stage_tile(const unsigned short* __restrict__ Ab,
                       const unsigned short* __restrict__ Bb,
                       int lda, int ldb, int k0, char* lb, int tid, int wave) {
#pragma unroll
  for (int i = 0; i < 4; ++i) {
    const int c = (i << 8) + tid;            // chunk 0..1023 (16B each)
    const int r = c >> 3;                    // tile row 0..127
    const int sk = ((c & 7) ^ (r & 7)) << 3; // pre-swizzled k-offset (shorts)
    char* la = lb + (((i << 8) + (wave << 6)) << 4);  // wave-uniform dest + lane*16
    gload16(Ab + (long long)r * lda + k0 + sk, la);
    gload16(Bb + (long long)r * ldb + k0 + sk, la + 16384);
  }
}

template <int EPI>
__global__ __launch_bounds__(256, 2)
void gemm_bt(const unsigned short* __restrict__ A, int lda, long long sA,
             const unsigned short* __restrict__ B, int ldb, long long sB,
             void* __restrict__ Cv, int ldc, long long sC, int K,
             const float* __restrict__ bias, const float* __restrict__ resid,
             unsigned short* __restrict__ aux, int gx, int gy) {
  __shared__ char lds[65536];  // buf t: A tile @ t*32768, B tile @ t*32768+16384
  const int tid = threadIdx.x;
  const int wave = tid >> 6, lane = tid & 63;
  const int wr = wave >> 1, wc = wave & 1;

  // T1: bijective XCD-chunked remap (all launches have nwg % 8 == 0)
  const int nwg = gridDim.x;
  const int id0 = blockIdx.x;
  const int id = (id0 & 7) * (nwg >> 3) + (id0 >> 3);
  const int bn = id % gx;
  const int t1 = id / gx;
  const int bm = t1 % gy;
  const int bz = t1 / gy;

  const unsigned short* Ab = A + (long long)bz * sA + (long long)bm * 128 * lda;
  const unsigned short* Bb = B + (long long)bz * sB + (long long)bn * 128 * ldb;

  f32x4 acc[4][4] = {};
  const int frow = lane & 15;
  const int fkb = (lane >> 4) << 4;      // byte offset of lane's 16B within the 64B k-half
  const int swr = (frow & 7) << 4;       // read-side swizzle term
  const int NT = K >> 6;

  stage_tile(Ab, Bb, lda, ldb, 0, lds, tid, wave);
  stage_tile(Ab, Bb, lda, ldb, 64, lds + 32768, tid, wave);
  asm volatile("s_waitcnt vmcnt(8)" ::: "memory");  // tile 0 landed (tile 1 in flight)

  for (int kt = 0; kt < NT; ++kt) {
    const int cur = kt & 1;
    __builtin_amdgcn_s_barrier();        // bar1: tile kt staged by ALL waves
    asm volatile("" ::: "memory");
    const char* lb = lds + cur * 32768;
    __builtin_amdgcn_s_setprio(1);
#pragma unroll
    for (int ks = 0; ks < 2; ++ks) {
      bf16x8 af[4], bfr[4];
      const int kb = (ks << 6) + fkb;
#pragma unroll
      for (int f = 0; f < 4; ++f) {
        const int ar = (wr << 6) + (f << 4) + frow;
        af[f] = *reinterpret_cast<const bf16x8*>(lb + ar * 128 + (kb ^ swr));
        const int br = (wc << 6) + (f << 4) + frow;
        bfr[f] = *reinterpret_cast<const bf16x8*>(lb + 16384 + br * 128 + (kb ^ swr));
      }
#pragma unroll
      for (int i = 0; i < 4; ++i)
#pragma unroll
        for (int j = 0; j < 4; ++j)
          acc[i][j] = __builtin_amdgcn_mfma_f32_16x16x32_bf16(af[i], bfr[j], acc[i][j], 0, 0, 0);
    }
    __builtin_amdgcn_s_setprio(0);
    asm volatile("" ::: "memory");
    __builtin_amdgcn_s_barrier();        // bar2: all waves done reading buf[cur]
    if (kt + 2 < NT) {
      stage_tile(Ab, Bb, lda, ldb, (kt + 2) << 6, lds + cur * 32768, tid, wave);
      asm volatile("s_waitcnt vmcnt(8)" ::: "memory");  // tile kt+1 landed
    } else if (kt + 2 == NT) {
      asm volatile("s_waitcnt vmcnt(0)" ::: "memory");  // last tile landed
    }
  }

  // epilogue: C row = (lane>>4)*4 + reg, col = lane&15 (verified m89/m91; R3/R4 passed)
  const int rb = bm * 128 + (wr << 6) + ((lane >> 4) << 2);
  const int cb = bn * 128 + (wc << 6) + (lane & 15);
#pragma unroll
  for (int i = 0; i < 4; ++i) {
#pragma unroll
    for (int j = 0; j < 4; ++j) {
      const int col = cb + (j << 4);
      if constexpr (EPI == EPI_QKV) {
        if (col >= 1024) {  // V: write transposed to vt[b][col-1024][p], packed x4 along p
          const int row0 = rb + (i << 4);
          const int bb = row0 >> 10, p0 = row0 & 1023;
          u16x4 o;
#pragma unroll
          for (int r = 0; r < 4; ++r) o[r] = f2b(acc[i][j][r] + bias[col]);
          *(u16x4*)(aux + (long long)bb * 524288 + (long long)(col - 1024) * 1024 + p0) = o;
          continue;
        }
      }
#pragma unroll
      for (int r = 0; r < 4; ++r) {
        const int row = rb + (i << 4) + r;
        float v = acc[i][j][r];
        if constexpr (EPI == EPI_BF16) {
          ((unsigned short*)Cv)[(long long)bz * sC + (long long)row * ldc + col] = f2b(v);
        } else if constexpr (EPI == EPI_QKV) {
          v += bias[col];
          if (col < 512) v *= RSQRT_C;  // fold attn scale into q
          ((unsigned short*)Cv)[(long long)row * ldc + col] = f2b(v);
        } else {  // EPI_PROJ: fp32 out + per-row bias + residual
          long long idx = (long long)bz * sC + (long long)row * ldc + col;
          ((float*)Cv)[idx] = v + bias[row] + resid[idx];
        }
      }
    }
  }
}

// ---------------- launch ----------------
extern "C" void kernel_launch(void* const* d_in, const int* in_sizes, int n_in,
                              void* d_out, int out_size, void* d_ws, size_t ws_size,
                              hipStream_t stream) {
  const float* x      = (const float*)d_in[0];
  const float* gn_w   = (const float*)d_in[1];
  const float* gn_b   = (const float*)d_in[2];
  const float* qkv_w  = (const float*)d_in[3];
  const float* qkv_b  = (const float*)d_in[4];
  const float* proj_w = (const float*)d_in[5];
  const float* proj_b = (const float*)d_in[6];

  char* ws = (char*)d_ws;
  unsigned short* wq   = (unsigned short*)(ws + 1024);      // 1536x512 bf16
  unsigned short* wp   = (unsigned short*)(ws + 1573888);   // 512x512 bf16
  unsigned short* h    = (unsigned short*)(ws + 2098176);   // (B,N,C) bf16 16.8MB
  unsigned short* qkv  = (unsigned short*)(ws + 18875392);  // (B,N,2C) q,k ld1024 33.6MB
  unsigned short* vt   = (unsigned short*)(ws + 52429824);  // (B,C,N) bf16 16.8MB [end 69.2MB]
  unsigned short* O    = h;                                 // h dead after QKV gemm
  unsigned short* S    = (unsigned short*)d_out;            // (B,N,N) bf16

  // both weight converts in one dispatch
  f2bf_all<<<1024, 256, 0, stream>>>(qkv_w, proj_w, wq, wp);
  // fused GroupNorm (stats + apply + transpose)
  gn_fused<<<128, 512, 0, stream>>>(x, gn_w, gn_b, h);
  // QKV: (16384x512) x (1536x512)^T; q,k -> qkv ld1024; v -> vt transposed
  gemm_bt<EPI_QKV><<<1536, 256, 0, stream>>>(
      h, 512, 0, wq, 512, 0, qkv, 1024, 0, 512, qkv_b, nullptr, vt, 12, 128);
  // S = q k^T per batch: grid 8x8x16 flattened
  gemm_bt<EPI_BF16><<<1024, 256, 0, stream>>>(
      qkv, 1024, 1024LL * 1024, qkv + 512, 1024, 1024LL * 1024,
      S, 1024, 1024LL * 1024, 512, nullptr, nullptr, nullptr, 8, 8);
  softmax_rows<<<4096, 256, 0, stream>>>(S);
  // O = P V: grid 4x8x16 flattened
  gemm_bt<EPI_BF16><<<512, 256, 0, stream>>>(
      S, 1024, 1024LL * 1024, vt, 1024, 512LL * 1024,
      O, 512, 1024LL * 512, 1024, nullptr, nullptr, nullptr, 4, 8);
  // proj (out^T form): grid 8x4x16 flattened
  gemm_bt<EPI_PROJ><<<512, 256, 0, stream>>>(
      wp, 512, 0, O, 512, 1024LL * 512,
      d_out, 1024, 512LL * 1024, 512, proj_b, x, nullptr, 8, 4);
}